// Round 2
// baseline (715.217 us; speedup 1.0000x reference)
//
#include <hip/hip_runtime.h>
#include <hip/hip_fp16.h>

// Problem constants (fixed by the reference)
constexpr int NN = 100000;          // nodes
constexpr int EE = 1600000;         // edges (without self loops)
constexpr int ET = EE + NN;         // edges + self loops
constexpr float NEG = 0.2f;

typedef _Float16 f16x8 __attribute__((ext_vector_type(8)));
typedef _Float16 f16x4 __attribute__((ext_vector_type(4)));
typedef float    f32x4 __attribute__((ext_vector_type(4)));

// ---------------------------------------------------------------------------
// CSR build: histogram -> scan -> scatter (scatter also records dst per slot)
// ---------------------------------------------------------------------------
__global__ __launch_bounds__(256) void k_count(const int* __restrict__ ei, int* __restrict__ deg) {
    int i = blockIdx.x * 256 + threadIdx.x;
    if (i >= ET) return;
    int dst = (i < EE) ? ei[EE + i] : (i - EE);
    atomicAdd(&deg[dst], 1);
}

__global__ __launch_bounds__(256) void k_part(const int* __restrict__ deg, int* __restrict__ part) {
    __shared__ int sh[256];
    int i = blockIdx.x * 256 + threadIdx.x;
    sh[threadIdx.x] = (i < NN) ? deg[i] : 0;
    __syncthreads();
    for (int o = 128; o; o >>= 1) {
        if (threadIdx.x < o) sh[threadIdx.x] += sh[threadIdx.x + o];
        __syncthreads();
    }
    if (threadIdx.x == 0) part[blockIdx.x] = sh[0];
}

__global__ __launch_bounds__(512) void k_scanp(int* __restrict__ part, int nb) {
    __shared__ int sh[512];
    int t = threadIdx.x;
    int v = (t < nb) ? part[t] : 0;
    sh[t] = v;
    __syncthreads();
    for (int o = 1; o < 512; o <<= 1) {
        int u = (t >= o) ? sh[t - o] : 0;
        __syncthreads();
        sh[t] += u;
        __syncthreads();
    }
    if (t < nb) part[t] = sh[t] - v;   // exclusive
}

__global__ __launch_bounds__(256) void k_scan(const int* __restrict__ deg, const int* __restrict__ part,
                                              int* __restrict__ rs, int* __restrict__ cur) {
    __shared__ int sh[256];
    int t = threadIdx.x;
    int i = blockIdx.x * 256 + t;
    int v = (i < NN) ? deg[i] : 0;
    sh[t] = v;
    __syncthreads();
    for (int o = 1; o < 256; o <<= 1) {
        int u = (t >= o) ? sh[t - o] : 0;
        __syncthreads();
        sh[t] += u;
        __syncthreads();
    }
    int incl = sh[t];
    int base = part[blockIdx.x];
    if (i < NN) {
        rs[i]  = base + incl - v;
        cur[i] = base + incl - v;
        if (i == NN - 1) rs[NN] = base + incl;
    }
}

__global__ __launch_bounds__(256) void k_scatter(const int* __restrict__ ei, int* __restrict__ cur,
                                                 int* __restrict__ csr, int* __restrict__ dstv) {
    int i = blockIdx.x * 256 + threadIdx.x;
    if (i >= ET) return;
    int src, dst;
    if (i < EE) { src = ei[i]; dst = ei[EE + i]; }
    else        { src = i - EE; dst = i - EE; }
    int pos = atomicAdd(&cur[dst], 1);
    csr[pos]  = src;
    dstv[pos] = dst;
}

// ---------------------------------------------------------------------------
// MFMA GEMM: xp = x @ W (fp16 inputs to matrix core, fp32 accumulate).
// ---------------------------------------------------------------------------
template <int K, int C, int OUT_MODE, bool SRCF32>
__global__ __launch_bounds__(256) void gemm_mfma(const void* __restrict__ xv, const float* __restrict__ W,
                                                 __half* __restrict__ xp, int n, int set_off) {
    constexpr int KC  = 64;          // K-chunk per stage
    constexpr int AST = KC + 8;      // padded LDS stride (halves)
    constexpr int NT  = C / 16;      // 16-col tiles
    constexpr int NST = K / KC;      // stages
    __shared__ _Float16 a_lds[128 * AST];
    __shared__ _Float16 w_lds[C * AST];

    const int tid  = threadIdx.x;
    const int w    = tid >> 6;
    const int lane = tid & 63;
    const int quad = lane >> 4;
    const int l16  = lane & 15;
    const long r0  = (long)blockIdx.x * 128;

    f32x4 acc[2][NT];
#pragma unroll
    for (int s = 0; s < 2; s++)
#pragma unroll
        for (int t = 0; t < NT; t++) acc[s][t] = (f32x4){0.f, 0.f, 0.f, 0.f};

    for (int st = 0; st < NST; ++st) {
        const int k0 = st * KC;
        // stage A: 128 rows x KC halves (convert fp32->fp16 if needed)
        for (int i = tid; i < 128 * (KC / 4); i += 256) {
            int r = i / (KC / 4);
            int q = i % (KC / 4);
            long row = r0 + r;
            f16x4 hv = (f16x4){0, 0, 0, 0};
            if (row < n) {
                if (SRCF32) {
                    float4 v = ((const float4*)xv)[row * (K / 4) + (k0 / 4) + q];
                    hv = (f16x4){(_Float16)v.x, (_Float16)v.y, (_Float16)v.z, (_Float16)v.w};
                } else {
                    hv = ((const f16x4*)xv)[row * (K / 4) + (k0 / 4) + q];
                }
            }
            *(f16x4*)&a_lds[r * AST + q * 4] = hv;
        }
        // stage W^T: w_lds[n][k] from W[k][n] (coalesced global reads over n)
        for (int i = tid; i < C * (KC / 4); i += 256) {
            int nn = i / (KC / 4);
            int kq = i % (KC / 4);
            f16x4 hv;
            hv.x = (_Float16)W[(long)(k0 + kq * 4 + 0) * C + nn];
            hv.y = (_Float16)W[(long)(k0 + kq * 4 + 1) * C + nn];
            hv.z = (_Float16)W[(long)(k0 + kq * 4 + 2) * C + nn];
            hv.w = (_Float16)W[(long)(k0 + kq * 4 + 3) * C + nn];
            *(f16x4*)&w_lds[nn * AST + kq * 4] = hv;
        }
        __syncthreads();

#pragma unroll
        for (int ks = 0; ks < KC; ks += 32) {
            f16x8 a0 = *(const f16x8*)&a_lds[(w * 32 + l16) * AST + ks + quad * 8];
            f16x8 a1 = *(const f16x8*)&a_lds[(w * 32 + 16 + l16) * AST + ks + quad * 8];
#pragma unroll
            for (int t = 0; t < NT; t++) {
                f16x8 b = *(const f16x8*)&w_lds[(t * 16 + l16) * AST + ks + quad * 8];
                acc[0][t] = __builtin_amdgcn_mfma_f32_16x16x32_f16(a0, b, acc[0][t], 0, 0, 0);
                acc[1][t] = __builtin_amdgcn_mfma_f32_16x16x32_f16(a1, b, acc[1][t], 0, 0, 0);
            }
        }
        __syncthreads();
    }

    // epilogue: C/D layout col=l16, row=quad*4+reg
#pragma unroll
    for (int sub = 0; sub < 2; sub++) {
        long rb = r0 + w * 32 + sub * 16 + quad * 4;
#pragma unroll
        for (int t = 0; t < NT; t++) {
            int c = t * 16 + l16;
#pragma unroll
            for (int rg = 0; rg < 4; rg++) {
                long row = rb + rg;
                if (row < n) {
                    __half hv = __float2half(acc[sub][t][rg]);
                    if (OUT_MODE == 0)
                        xp[row * 256 + ((c >> 1) << 2) + (c & 1) + set_off] = hv;
                    else
                        xp[row * (long)C + c] = hv;
                }
            }
        }
    }
}

// ---------------------------------------------------------------------------
// Fused attention coefficients for conv1 from packed fp16 xpc.
// ---------------------------------------------------------------------------
__global__ __launch_bounds__(256) void attn1_fused(const __half2* __restrict__ xpc,
                                                   const float* __restrict__ as_w, const float* __restrict__ ad_w,
                                                   float2* __restrict__ att_s, float2* __restrict__ att_d, int n) {
    int idx = blockIdx.x * 256 + threadIdx.x;
    if (idx >= n * 4) return;
    int v = idx >> 2, hh = idx & 3;
    const __half2* row = xpc + (long)v * 128 + hh * 32;   // 16 chunks x 2 half2
    const float* a1 = as_w + hh * 32;
    const float* a2 = ad_w + hh * 32;
    float sp1 = 0.f, sp2 = 0.f, sg1 = 0.f, sg2 = 0.f;
#pragma unroll
    for (int t = 0; t < 16; t++) {
        float2 fp = __half22float2(row[2 * t]);
        float2 fg = __half22float2(row[2 * t + 1]);
        float2 w1 = *(const float2*)(a1 + 2 * t);
        float2 w2 = *(const float2*)(a2 + 2 * t);
        sp1 += fp.x * w1.x + fp.y * w1.y;
        sp2 += fp.x * w2.x + fp.y * w2.y;
        sg1 += fg.x * w1.x + fg.y * w1.y;
        sg2 += fg.x * w2.x + fg.y * w2.y;
    }
    att_s[idx] = make_float2(sp1, sg1);
    att_d[idx] = make_float2(sp2, sg2);
}

// attention for conv2 (H=1, C=64), fp16 xp
__global__ __launch_bounds__(256) void attn2_kernel(const __half2* __restrict__ xp,
                                                    const float* __restrict__ as_w, const float* __restrict__ ad_w,
                                                    float* __restrict__ asrc, float* __restrict__ adst, int n) {
    int v = blockIdx.x * 256 + threadIdx.x;
    if (v >= n) return;
    const __half2* p = xp + (long)v * 32;
    float s1 = 0.f, s2 = 0.f;
#pragma unroll
    for (int c = 0; c < 32; c++) {
        float2 xv = __half22float2(p[c]);
        float2 w1 = *(const float2*)(as_w + 2 * c);
        float2 w2 = *(const float2*)(ad_w + 2 * c);
        s1 += xv.x * w1.x + xv.y * w1.y;
        s2 += xv.x * w2.x + xv.y * w2.y;
    }
    asrc[v] = s1;
    adst[v] = s2;
}

// ---------------------------------------------------------------------------
// Per-edge exp-weight precompute for conv1 (8 weights/edge, 32 B sequential).
// ---------------------------------------------------------------------------
__global__ __launch_bounds__(256) void w1prep(const int* __restrict__ csr, const int* __restrict__ dstv,
                                              const float4* __restrict__ att_s4, const float4* __restrict__ att_d4,
                                              float4* __restrict__ wb4) {
    int j = blockIdx.x * 256 + threadIdx.x;
    if (j >= ET) return;
    int s = csr[j], v = dstv[j];
    float4 s0 = att_s4[s * 2], s1 = att_s4[s * 2 + 1];
    float4 d0 = att_d4[v * 2], d1 = att_d4[v * 2 + 1];
    auto w = [](float e) { e = (e > 0.f) ? e : NEG * e; return __expf(e); };
    float4 w0, w1;
    w0.x = w(s0.x + d0.x); w0.y = w(s0.y + d0.y);
    w0.z = w(s0.z + d0.z); w0.w = w(s0.w + d0.w);
    w1.x = w(s1.x + d1.x); w1.y = w(s1.y + d1.y);
    w1.z = w(s1.z + d1.z); w1.w = w(s1.w + d1.w);
    wb4[j * 2]     = w0;
    wb4[j * 2 + 1] = w1;
}

// Per-edge exp-weight for conv2 (H=1): 4 B/edge.
__global__ __launch_bounds__(256) void w2prep(const int* __restrict__ csr, const int* __restrict__ dstv,
                                              const float* __restrict__ asrc, const float* __restrict__ adst,
                                              float* __restrict__ w2b) {
    int j = blockIdx.x * 256 + threadIdx.x;
    if (j >= ET) return;
    float e = asrc[csr[j]] + adst[dstv[j]];
    e = (e > 0.f) ? e : NEG * e;
    w2b[j] = __expf(e);
}

// ---------------------------------------------------------------------------
// Fused single-pass conv1 edge kernel, v3.
// One wave per dst node; two 32-lane halves; each half gathers a FULL 512B
// packed row per 16B-lane load (uint4). v3: steady-state chunk is 16 edges
// = EIGHT uint4 gathers in flight per wave (latency-bound fix; v2 had 4),
// then an 8-edge middle chunk, then a 2-edge predicated tail.
// Final cross-half combine: 10x shfl_xor(32) once per node.
// ---------------------------------------------------------------------------
__global__ __launch_bounds__(256) void conv1_edge_fused(const int* __restrict__ rs, const int* __restrict__ csr,
                                                        const uint4* __restrict__ xpc,
                                                        const float2* __restrict__ wb,
                                                        const float* __restrict__ bias,
                                                        __half* __restrict__ out) {
    int v = blockIdx.x * 4 + (threadIdx.x >> 6);
    if (v >= NN) return;
    int lane = threadIdx.x & 63;
    int h = lane >> 5;                 // half-wave: 0 -> even edges, 1 -> odd edges
    int m = lane & 31;                 // lane within half; channels 4m..4m+3
    int hd = m >> 3;                   // head index
    int e0 = rs[v], e1 = rs[v + 1];

    float ap0 = 0.f, ap1 = 0.f, ap2 = 0.f, ap3 = 0.f;
    float ag0 = 0.f, ag1 = 0.f, ag2 = 0.f, ag3 = 0.f;
    float dp = 0.f, dg = 0.f;

    int j = e0;
    // deep chunks: 16 edges, 8 gathers in flight, no predication
    for (; j + 16 <= e1; j += 16) {
        int s[8]; float2 wv[8]; uint4 r[8];
#pragma unroll
        for (int q = 0; q < 8; q++) s[q] = csr[j + 2 * q + h];
#pragma unroll
        for (int q = 0; q < 8; q++) wv[q] = wb[(j + 2 * q + h) * 4 + hd];
#pragma unroll
        for (int q = 0; q < 8; q++) r[q] = xpc[(long)s[q] * 32 + m];
#pragma unroll
        for (int q = 0; q < 8; q++) {
            float wx = wv[q].x, wy = wv[q].y;
            dp += wx; dg += wy;
            float2 p01 = __half22float2(*(__half2*)&r[q].x);
            float2 g01 = __half22float2(*(__half2*)&r[q].y);
            float2 p23 = __half22float2(*(__half2*)&r[q].z);
            float2 g23 = __half22float2(*(__half2*)&r[q].w);
            ap0 += wx * p01.x; ap1 += wx * p01.y; ap2 += wx * p23.x; ap3 += wx * p23.y;
            ag0 += wy * g01.x; ag1 += wy * g01.y; ag2 += wy * g23.x; ag3 += wy * g23.y;
        }
    }
    // middle chunk: 8 edges, 4 gathers, no predication
    for (; j + 8 <= e1; j += 8) {
        int s[4]; float2 wv[4]; uint4 r[4];
#pragma unroll
        for (int q = 0; q < 4; q++) s[q] = csr[j + 2 * q + h];
#pragma unroll
        for (int q = 0; q < 4; q++) wv[q] = wb[(j + 2 * q + h) * 4 + hd];
#pragma unroll
        for (int q = 0; q < 4; q++) r[q] = xpc[(long)s[q] * 32 + m];
#pragma unroll
        for (int q = 0; q < 4; q++) {
            float wx = wv[q].x, wy = wv[q].y;
            dp += wx; dg += wy;
            float2 p01 = __half22float2(*(__half2*)&r[q].x);
            float2 g01 = __half22float2(*(__half2*)&r[q].y);
            float2 p23 = __half22float2(*(__half2*)&r[q].z);
            float2 g23 = __half22float2(*(__half2*)&r[q].w);
            ap0 += wx * p01.x; ap1 += wx * p01.y; ap2 += wx * p23.x; ap3 += wx * p23.y;
            ag0 += wy * g01.x; ag1 += wy * g01.y; ag2 += wy * g23.x; ag3 += wy * g23.y;
        }
    }
    // tail: 2 edges per iteration, clamped duplicate gathers with zero weight
    for (; j < e1; j += 2) {
        int jj = j + h;
        int jc = (jj < e1) ? jj : (e1 - 1);
        bool ok = jj < e1;
        int s = csr[jc];
        float2 wv = wb[jc * 4 + hd];
        uint4 r = xpc[(long)s * 32 + m];
        float wx = ok ? wv.x : 0.f;
        float wy = ok ? wv.y : 0.f;
        dp += wx; dg += wy;
        float2 p01 = __half22float2(*(__half2*)&r.x);
        float2 g01 = __half22float2(*(__half2*)&r.y);
        float2 p23 = __half22float2(*(__half2*)&r.z);
        float2 g23 = __half22float2(*(__half2*)&r.w);
        ap0 += wx * p01.x; ap1 += wx * p01.y; ap2 += wx * p23.x; ap3 += wx * p23.y;
        ag0 += wy * g01.x; ag1 += wy * g01.y; ag2 += wy * g23.x; ag3 += wy * g23.y;
    }

    // combine the two halves (independent edge subsets)
    ap0 += __shfl_xor(ap0, 32); ap1 += __shfl_xor(ap1, 32);
    ap2 += __shfl_xor(ap2, 32); ap3 += __shfl_xor(ap3, 32);
    ag0 += __shfl_xor(ag0, 32); ag1 += __shfl_xor(ag1, 32);
    ag2 += __shfl_xor(ag2, 32); ag3 += __shfl_xor(ag3, 32);
    dp  += __shfl_xor(dp, 32);  dg  += __shfl_xor(dg, 32);

    float ivp = 1.0f / dp, ivg = 1.0f / dg;
    int c0 = 4 * m;
    float4 b4 = *(const float4*)&bias[c0];
    // half 0 writes the p-set, half 1 writes the g-set (same channels)
    float inv = h ? ivg : ivp;
    float a0 = h ? ag0 : ap0;
    float a1 = h ? ag1 : ap1;
    float a2 = h ? ag2 : ap2;
    float a3 = h ? ag3 : ap3;
    __half2 o01 = __floats2half2_rn(fmaxf(a0 * inv + b4.x, 0.f), fmaxf(a1 * inv + b4.y, 0.f));
    __half2 o23 = __floats2half2_rn(fmaxf(a2 * inv + b4.z, 0.f), fmaxf(a3 * inv + b4.w, 0.f));
    uint2 st;
    st.x = *(unsigned int*)&o01;
    st.y = *(unsigned int*)&o23;
    *(uint2*)(out + (long)v * 256 + h * 128 + c0) = st;
}

// ---------------------------------------------------------------------------
// Single-pass conv2 edge kernel v3 (H=1, C=64, fp16 xp).
// Quarter-waves: lane qw=lane>>4 handles edges j+4k+qw; lane m=lane&15 gathers
// 8B (channels 4m..4m+3). v3: steady-state chunk 32 edges = EIGHT uint2
// gathers in flight, then 16-edge middle, then 4-edge clamped tail.
// Combine via shfl_xor(16)+shfl_xor(32); lanes 0..15 write float4.
// ---------------------------------------------------------------------------
__global__ __launch_bounds__(256) void conv2_edge(const int* __restrict__ rs, const int* __restrict__ csr,
                                                  const __half* __restrict__ xp,
                                                  const float* __restrict__ w2b,
                                                  const float* __restrict__ bias,
                                                  float* __restrict__ out) {
    int v = blockIdx.x * 4 + (threadIdx.x >> 6);
    if (v >= NN) return;
    int lane = threadIdx.x & 63;
    int qw = lane >> 4;                // quarter-wave: edge offset
    int m = lane & 15;                 // channels 4m..4m+3
    int e0 = rs[v], e1 = rs[v + 1];
    const uint2* xp2 = (const uint2*)xp;

    float a0 = 0.f, a1 = 0.f, a2 = 0.f, a3 = 0.f, d = 0.f;

    int j = e0;
    // deep chunks: 32 edges, 8 gathers in flight, no predication
    for (; j + 32 <= e1; j += 32) {
        int s[8]; float w[8]; uint2 r[8];
#pragma unroll
        for (int k = 0; k < 8; k++) s[k] = csr[j + 4 * k + qw];
#pragma unroll
        for (int k = 0; k < 8; k++) w[k] = w2b[j + 4 * k + qw];
#pragma unroll
        for (int k = 0; k < 8; k++) r[k] = xp2[(long)s[k] * 16 + m];
#pragma unroll
        for (int k = 0; k < 8; k++) {
            d += w[k];
            float2 x01 = __half22float2(*(__half2*)&r[k].x);
            float2 x23 = __half22float2(*(__half2*)&r[k].y);
            a0 += w[k] * x01.x; a1 += w[k] * x01.y;
            a2 += w[k] * x23.x; a3 += w[k] * x23.y;
        }
    }
    // middle chunk: 16 edges, 4 gathers, no predication
    for (; j + 16 <= e1; j += 16) {
        int s[4]; float w[4]; uint2 r[4];
#pragma unroll
        for (int k = 0; k < 4; k++) s[k] = csr[j + 4 * k + qw];
#pragma unroll
        for (int k = 0; k < 4; k++) w[k] = w2b[j + 4 * k + qw];
#pragma unroll
        for (int k = 0; k < 4; k++) r[k] = xp2[(long)s[k] * 16 + m];
#pragma unroll
        for (int k = 0; k < 4; k++) {
            d += w[k];
            float2 x01 = __half22float2(*(__half2*)&r[k].x);
            float2 x23 = __half22float2(*(__half2*)&r[k].y);
            a0 += w[k] * x01.x; a1 += w[k] * x01.y;
            a2 += w[k] * x23.x; a3 += w[k] * x23.y;
        }
    }
    // tail: 4 edges per iteration, clamped
    for (; j < e1; j += 4) {
        int jj = j + qw;
        int jc = (jj < e1) ? jj : (e1 - 1);
        int s = csr[jc];
        float w = ((jj < e1) ? w2b[jc] : 0.f);
        uint2 r = xp2[(long)s * 16 + m];
        d += w;
        float2 x01 = __half22float2(*(__half2*)&r.x);
        float2 x23 = __half22float2(*(__half2*)&r.y);
        a0 += w * x01.x; a1 += w * x01.y;
        a2 += w * x23.x; a3 += w * x23.y;
    }

    // combine the four quarters
    a0 += __shfl_xor(a0, 16); a1 += __shfl_xor(a1, 16);
    a2 += __shfl_xor(a2, 16); a3 += __shfl_xor(a3, 16);
    d  += __shfl_xor(d, 16);
    a0 += __shfl_xor(a0, 32); a1 += __shfl_xor(a1, 32);
    a2 += __shfl_xor(a2, 32); a3 += __shfl_xor(a3, 32);
    d  += __shfl_xor(d, 32);

    if (qw == 0) {
        float inv = 1.0f / d;
        float4 b4 = *(const float4*)&bias[4 * m];
        float4 o;
        o.x = a0 * inv + b4.x;
        o.y = a1 * inv + b4.y;
        o.z = a2 * inv + b4.z;
        o.w = a3 * inv + b4.w;
        *(float4*)&out[(long)v * 64 + 4 * m] = o;
    }
}

// ---------------------------------------------------------------------------
// Launch
// ---------------------------------------------------------------------------
extern "C" void kernel_launch(void* const* d_in, const int* in_sizes, int n_in,
                              void* d_out, int out_size, void* d_ws, size_t ws_size,
                              hipStream_t stream) {
    const float* x_ppi = (const float*)d_in[0];
    const float* x_go  = (const float*)d_in[1];
    const int*   ei    = (const int*)d_in[2];
    const float* W1    = (const float*)d_in[3];
    const float* as1   = (const float*)d_in[4];
    const float* ad1   = (const float*)d_in[5];
    const float* b1    = (const float*)d_in[6];
    const float* W2    = (const float*)d_in[7];
    const float* as2   = (const float*)d_in[8];
    const float* ad2   = (const float*)d_in[9];
    const float* b2    = (const float*)d_in[10];
    float* out = (float*)d_out;

    char* ws = (char*)d_ws;
    size_t off = 0;
    auto alloc = [&](size_t bytes) -> void* {
        void* p = ws + off;
        off = (off + bytes + 255) & ~(size_t)255;
        return p;
    };
    int* deg     = (int*)alloc((size_t)NN * 4);
    int* rs      = (int*)alloc((size_t)(NN + 1) * 4);
    int* cur     = (int*)alloc((size_t)NN * 4);
    int* part    = (int*)alloc(512 * 4);
    int* csr     = (int*)alloc((size_t)ET * 4);
    int* dstv    = (int*)alloc((size_t)ET * 4);
    __half* xpc  = (__half*)alloc((size_t)NN * 256 * 2);   // packed {p0,p1,g0,g1} fp16
    __half* xp2  = (__half*)alloc((size_t)NN * 64 * 2);    // conv2 features fp16
    float2* atts = (float2*)alloc((size_t)NN * 4 * 8);
    float2* attd = (float2*)alloc((size_t)NN * 4 * 8);
    float* asr2  = (float*)alloc((size_t)NN * 4);
    float* ads2  = (float*)alloc((size_t)NN * 4);
    float* wb1   = (float*)alloc((size_t)ET * 32);         // 8 fp32 weights / edge
    float* w2b   = (float*)alloc((size_t)ET * 4);
    __half* hbuf = (__half*)alloc((size_t)NN * 256 * 2);   // conv1 output, fp16
    (void)ws_size; (void)in_sizes; (void)n_in; (void)out_size;

    const int NB = (NN + 255) / 256;        // 391
    const int EB = (ET + 255) / 256;        // 6641
    const int GB = (NN + 127) / 128;        // 782 (MFMA gemm blocks)

    // CSR build (shared by all three convs)
    hipMemsetAsync(deg, 0, (size_t)NN * 4, stream);
    k_count<<<EB, 256, 0, stream>>>(ei, deg);
    k_part<<<NB, 256, 0, stream>>>(deg, part);
    k_scanp<<<1, 512, 0, stream>>>(part, NB);
    k_scan<<<NB, 256, 0, stream>>>(deg, part, rs, cur);
    k_scatter<<<EB, 256, 0, stream>>>(ei, cur, csr, dstv);

    // layer 1: two MFMA GEMMs into packed fp16, fused attn, weight prep, edge conv
    gemm_mfma<128, 128, 0, true><<<GB, 256, 0, stream>>>(x_ppi, W1, xpc, NN, 0);
    gemm_mfma<128, 128, 0, true><<<GB, 256, 0, stream>>>(x_go, W1, xpc, NN, 2);
    attn1_fused<<<(NN * 4 + 255) / 256, 256, 0, stream>>>((const __half2*)xpc, as1, ad1, atts, attd, NN);
    w1prep<<<EB, 256, 0, stream>>>(csr, dstv, (const float4*)atts, (const float4*)attd, (float4*)wb1);
    conv1_edge_fused<<<NN / 4, 256, 0, stream>>>(rs, csr, (const uint4*)xpc, (const float2*)wb1, b1, hbuf);

    // layer 2
    gemm_mfma<256, 64, 1, false><<<GB, 256, 0, stream>>>(hbuf, W2, xp2, NN, 0);
    attn2_kernel<<<(NN + 255) / 256, 256, 0, stream>>>((const __half2*)xp2, as2, ad2, asr2, ads2, NN);
    w2prep<<<EB, 256, 0, stream>>>(csr, dstv, asr2, ads2, w2b);
    conv2_edge<<<NN / 4, 256, 0, stream>>>(rs, csr, xp2, w2b, b2, out);
}

// Round 3
// 682.389 us; speedup vs baseline: 1.0481x; 1.0481x over previous
//
#include <hip/hip_runtime.h>
#include <hip/hip_fp16.h>

// Problem constants (fixed by the reference)
constexpr int NN = 100000;          // nodes
constexpr int EE = 1600000;         // edges (without self loops)
constexpr int ET = EE + NN;         // edges + self loops
constexpr float NEG = 0.2f;

typedef _Float16 f16x8 __attribute__((ext_vector_type(8)));
typedef _Float16 f16x4 __attribute__((ext_vector_type(4)));
typedef float    f32x4 __attribute__((ext_vector_type(4)));

// ---------------------------------------------------------------------------
// CSR build: histogram -> scan -> scatter
// ---------------------------------------------------------------------------
__global__ __launch_bounds__(256) void k_count(const int* __restrict__ ei, int* __restrict__ deg) {
    int i = blockIdx.x * 256 + threadIdx.x;
    if (i >= ET) return;
    int dst = (i < EE) ? ei[EE + i] : (i - EE);
    atomicAdd(&deg[dst], 1);
}

__global__ __launch_bounds__(256) void k_part(const int* __restrict__ deg, int* __restrict__ part) {
    __shared__ int sh[256];
    int i = blockIdx.x * 256 + threadIdx.x;
    sh[threadIdx.x] = (i < NN) ? deg[i] : 0;
    __syncthreads();
    for (int o = 128; o; o >>= 1) {
        if (threadIdx.x < o) sh[threadIdx.x] += sh[threadIdx.x + o];
        __syncthreads();
    }
    if (threadIdx.x == 0) part[blockIdx.x] = sh[0];
}

__global__ __launch_bounds__(512) void k_scanp(int* __restrict__ part, int nb) {
    __shared__ int sh[512];
    int t = threadIdx.x;
    int v = (t < nb) ? part[t] : 0;
    sh[t] = v;
    __syncthreads();
    for (int o = 1; o < 512; o <<= 1) {
        int u = (t >= o) ? sh[t - o] : 0;
        __syncthreads();
        sh[t] += u;
        __syncthreads();
    }
    if (t < nb) part[t] = sh[t] - v;   // exclusive
}

__global__ __launch_bounds__(256) void k_scan(const int* __restrict__ deg, const int* __restrict__ part,
                                              int* __restrict__ rs, int* __restrict__ cur) {
    __shared__ int sh[256];
    int t = threadIdx.x;
    int i = blockIdx.x * 256 + t;
    int v = (i < NN) ? deg[i] : 0;
    sh[t] = v;
    __syncthreads();
    for (int o = 1; o < 256; o <<= 1) {
        int u = (t >= o) ? sh[t - o] : 0;
        __syncthreads();
        sh[t] += u;
        __syncthreads();
    }
    int incl = sh[t];
    int base = part[blockIdx.x];
    if (i < NN) {
        rs[i]  = base + incl - v;
        cur[i] = base + incl - v;
        if (i == NN - 1) rs[NN] = base + incl;
    }
}

__global__ __launch_bounds__(256) void k_scatter(const int* __restrict__ ei, int* __restrict__ cur,
                                                 int* __restrict__ csr) {
    int i = blockIdx.x * 256 + threadIdx.x;
    if (i >= ET) return;
    int src, dst;
    if (i < EE) { src = ei[i]; dst = ei[EE + i]; }
    else        { src = i - EE; dst = i - EE; }
    int pos = atomicAdd(&cur[dst], 1);
    csr[pos] = src;
}

// ---------------------------------------------------------------------------
// MFMA GEMM: xp = x @ W (fp16 inputs to matrix core, fp32 accumulate).
// ---------------------------------------------------------------------------
template <int K, int C, int OUT_MODE, bool SRCF32>
__global__ __launch_bounds__(256) void gemm_mfma(const void* __restrict__ xv, const float* __restrict__ W,
                                                 __half* __restrict__ xp, int n, int set_off) {
    constexpr int KC  = 64;          // K-chunk per stage
    constexpr int AST = KC + 8;      // padded LDS stride (halves)
    constexpr int NT  = C / 16;      // 16-col tiles
    constexpr int NST = K / KC;      // stages
    __shared__ _Float16 a_lds[128 * AST];
    __shared__ _Float16 w_lds[C * AST];

    const int tid  = threadIdx.x;
    const int w    = tid >> 6;
    const int lane = tid & 63;
    const int quad = lane >> 4;
    const int l16  = lane & 15;
    const long r0  = (long)blockIdx.x * 128;

    f32x4 acc[2][NT];
#pragma unroll
    for (int s = 0; s < 2; s++)
#pragma unroll
        for (int t = 0; t < NT; t++) acc[s][t] = (f32x4){0.f, 0.f, 0.f, 0.f};

    for (int st = 0; st < NST; ++st) {
        const int k0 = st * KC;
        // stage A: 128 rows x KC halves (convert fp32->fp16 if needed)
        for (int i = tid; i < 128 * (KC / 4); i += 256) {
            int r = i / (KC / 4);
            int q = i % (KC / 4);
            long row = r0 + r;
            f16x4 hv = (f16x4){0, 0, 0, 0};
            if (row < n) {
                if (SRCF32) {
                    float4 v = ((const float4*)xv)[row * (K / 4) + (k0 / 4) + q];
                    hv = (f16x4){(_Float16)v.x, (_Float16)v.y, (_Float16)v.z, (_Float16)v.w};
                } else {
                    hv = ((const f16x4*)xv)[row * (K / 4) + (k0 / 4) + q];
                }
            }
            *(f16x4*)&a_lds[r * AST + q * 4] = hv;
        }
        // stage W^T: w_lds[n][k] from W[k][n] (coalesced global reads over n)
        for (int i = tid; i < C * (KC / 4); i += 256) {
            int nn = i / (KC / 4);
            int kq = i % (KC / 4);
            f16x4 hv;
            hv.x = (_Float16)W[(long)(k0 + kq * 4 + 0) * C + nn];
            hv.y = (_Float16)W[(long)(k0 + kq * 4 + 1) * C + nn];
            hv.z = (_Float16)W[(long)(k0 + kq * 4 + 2) * C + nn];
            hv.w = (_Float16)W[(long)(k0 + kq * 4 + 3) * C + nn];
            *(f16x4*)&w_lds[nn * AST + kq * 4] = hv;
        }
        __syncthreads();

#pragma unroll
        for (int ks = 0; ks < KC; ks += 32) {
            f16x8 a0 = *(const f16x8*)&a_lds[(w * 32 + l16) * AST + ks + quad * 8];
            f16x8 a1 = *(const f16x8*)&a_lds[(w * 32 + 16 + l16) * AST + ks + quad * 8];
#pragma unroll
            for (int t = 0; t < NT; t++) {
                f16x8 b = *(const f16x8*)&w_lds[(t * 16 + l16) * AST + ks + quad * 8];
                acc[0][t] = __builtin_amdgcn_mfma_f32_16x16x32_f16(a0, b, acc[0][t], 0, 0, 0);
                acc[1][t] = __builtin_amdgcn_mfma_f32_16x16x32_f16(a1, b, acc[1][t], 0, 0, 0);
            }
        }
        __syncthreads();
    }

    // epilogue: C/D layout col=l16, row=quad*4+reg
#pragma unroll
    for (int sub = 0; sub < 2; sub++) {
        long rb = r0 + w * 32 + sub * 16 + quad * 4;
#pragma unroll
        for (int t = 0; t < NT; t++) {
            int c = t * 16 + l16;
#pragma unroll
            for (int rg = 0; rg < 4; rg++) {
                long row = rb + rg;
                if (row < n) {
                    __half hv = __float2half(acc[sub][t][rg]);
                    if (OUT_MODE == 0)
                        xp[row * 256 + ((c >> 1) << 2) + (c & 1) + set_off] = hv;
                    else
                        xp[row * (long)C + c] = hv;
                }
            }
        }
    }
}

// ---------------------------------------------------------------------------
// Fused attention coefficients for conv1 from packed fp16 xpc.
// att_s[v*4+h] = {p-set src score, g-set src score} for head h; att_d same.
// ---------------------------------------------------------------------------
__global__ __launch_bounds__(256) void attn1_fused(const __half2* __restrict__ xpc,
                                                   const float* __restrict__ as_w, const float* __restrict__ ad_w,
                                                   float2* __restrict__ att_s, float2* __restrict__ att_d, int n) {
    int idx = blockIdx.x * 256 + threadIdx.x;
    if (idx >= n * 4) return;
    int v = idx >> 2, hh = idx & 3;
    const __half2* row = xpc + (long)v * 128 + hh * 32;   // 16 chunks x 2 half2
    const float* a1 = as_w + hh * 32;
    const float* a2 = ad_w + hh * 32;
    float sp1 = 0.f, sp2 = 0.f, sg1 = 0.f, sg2 = 0.f;
#pragma unroll
    for (int t = 0; t < 16; t++) {
        float2 fp = __half22float2(row[2 * t]);
        float2 fg = __half22float2(row[2 * t + 1]);
        float2 w1 = *(const float2*)(a1 + 2 * t);
        float2 w2 = *(const float2*)(a2 + 2 * t);
        sp1 += fp.x * w1.x + fp.y * w1.y;
        sp2 += fp.x * w2.x + fp.y * w2.y;
        sg1 += fg.x * w1.x + fg.y * w1.y;
        sg2 += fg.x * w2.x + fg.y * w2.y;
    }
    att_s[idx] = make_float2(sp1, sg1);
    att_d[idx] = make_float2(sp2, sg2);
}

// attention for conv2 (H=1, C=64), fp16 xp
__global__ __launch_bounds__(256) void attn2_kernel(const __half2* __restrict__ xp,
                                                    const float* __restrict__ as_w, const float* __restrict__ ad_w,
                                                    float* __restrict__ asrc, float* __restrict__ adst, int n) {
    int v = blockIdx.x * 256 + threadIdx.x;
    if (v >= n) return;
    const __half2* p = xp + (long)v * 32;
    float s1 = 0.f, s2 = 0.f;
#pragma unroll
    for (int c = 0; c < 32; c++) {
        float2 xv = __half22float2(p[c]);
        float2 w1 = *(const float2*)(as_w + 2 * c);
        float2 w2 = *(const float2*)(ad_w + 2 * c);
        s1 += xv.x * w1.x + xv.y * w1.y;
        s2 += xv.x * w2.x + xv.y * w2.y;
    }
    asrc[v] = s1;
    adst[v] = s2;
}

// ---------------------------------------------------------------------------
// Fused single-pass conv1 edge kernel, v4.
// v2 chunk structure (8 edges / 4 gathers in flight — proven best) with the
// edge weight computed INLINE: gather att_s[s] (8B/lane, 3.2MB table ->
// L2-resident) + per-node att_d[v] in registers, then exp(lrelu(.)).
// This removes the streamed wb1 reads (32B/edge of L2-miss traffic) and the
// entire w1prep kernel.
// One wave per dst node; two 32-lane halves; each half gathers a FULL 512B
// packed row per 16B-lane load (uint4). Half h takes edges j+2q+h; lane m
// carries channels 4m..4m+3 of both sets. Tail: clamped gathers, zeroed w.
// Final cross-half combine: 10x shfl_xor(32).
// ---------------------------------------------------------------------------
__global__ __launch_bounds__(256) void conv1_edge_fused(const int* __restrict__ rs, const int* __restrict__ csr,
                                                        const uint4* __restrict__ xpc,
                                                        const float2* __restrict__ att_s,
                                                        const float2* __restrict__ att_d,
                                                        const float* __restrict__ bias,
                                                        __half* __restrict__ out) {
    int v = blockIdx.x * 4 + (threadIdx.x >> 6);
    if (v >= NN) return;
    int lane = threadIdx.x & 63;
    int h = lane >> 5;                 // half-wave: 0 -> even edges, 1 -> odd edges
    int m = lane & 31;                 // lane within half; channels 4m..4m+3
    int hd = m >> 3;                   // head index
    int e0 = rs[v], e1 = rs[v + 1];

    float2 ad = att_d[v * 4 + hd];     // dst scores for this head {p, g}

    float ap0 = 0.f, ap1 = 0.f, ap2 = 0.f, ap3 = 0.f;
    float ag0 = 0.f, ag1 = 0.f, ag2 = 0.f, ag3 = 0.f;
    float dp = 0.f, dg = 0.f;

    auto lrexp = [](float e) { e = (e > 0.f) ? e : NEG * e; return __expf(e); };

    int j = e0;
    // full chunks: 8 edges, 4 gathers in flight, no predication
    for (; j + 8 <= e1; j += 8) {
        int s[4]; float2 av[4]; uint4 r[4];
#pragma unroll
        for (int q = 0; q < 4; q++) s[q] = csr[j + 2 * q + h];
#pragma unroll
        for (int q = 0; q < 4; q++) av[q] = att_s[s[q] * 4 + hd];
#pragma unroll
        for (int q = 0; q < 4; q++) r[q] = xpc[(long)s[q] * 32 + m];
#pragma unroll
        for (int q = 0; q < 4; q++) {
            float wx = lrexp(av[q].x + ad.x);
            float wy = lrexp(av[q].y + ad.y);
            dp += wx; dg += wy;
            float2 p01 = __half22float2(*(__half2*)&r[q].x);
            float2 g01 = __half22float2(*(__half2*)&r[q].y);
            float2 p23 = __half22float2(*(__half2*)&r[q].z);
            float2 g23 = __half22float2(*(__half2*)&r[q].w);
            ap0 += wx * p01.x; ap1 += wx * p01.y; ap2 += wx * p23.x; ap3 += wx * p23.y;
            ag0 += wy * g01.x; ag1 += wy * g01.y; ag2 += wy * g23.x; ag3 += wy * g23.y;
        }
    }
    // tail: 2 edges per iteration, clamped duplicate gathers with zero weight
    for (; j < e1; j += 2) {
        int jj = j + h;
        int jc = (jj < e1) ? jj : (e1 - 1);
        bool ok = jj < e1;
        int s = csr[jc];
        float2 av = att_s[s * 4 + hd];
        uint4 r = xpc[(long)s * 32 + m];
        float wx = ok ? lrexp(av.x + ad.x) : 0.f;
        float wy = ok ? lrexp(av.y + ad.y) : 0.f;
        dp += wx; dg += wy;
        float2 p01 = __half22float2(*(__half2*)&r.x);
        float2 g01 = __half22float2(*(__half2*)&r.y);
        float2 p23 = __half22float2(*(__half2*)&r.z);
        float2 g23 = __half22float2(*(__half2*)&r.w);
        ap0 += wx * p01.x; ap1 += wx * p01.y; ap2 += wx * p23.x; ap3 += wx * p23.y;
        ag0 += wy * g01.x; ag1 += wy * g01.y; ag2 += wy * g23.x; ag3 += wy * g23.y;
    }

    // combine the two halves (independent edge subsets)
    ap0 += __shfl_xor(ap0, 32); ap1 += __shfl_xor(ap1, 32);
    ap2 += __shfl_xor(ap2, 32); ap3 += __shfl_xor(ap3, 32);
    ag0 += __shfl_xor(ag0, 32); ag1 += __shfl_xor(ag1, 32);
    ag2 += __shfl_xor(ag2, 32); ag3 += __shfl_xor(ag3, 32);
    dp  += __shfl_xor(dp, 32);  dg  += __shfl_xor(dg, 32);

    float ivp = 1.0f / dp, ivg = 1.0f / dg;
    int c0 = 4 * m;
    float4 b4 = *(const float4*)&bias[c0];
    // half 0 writes the p-set, half 1 writes the g-set (same channels)
    float inv = h ? ivg : ivp;
    float a0 = h ? ag0 : ap0;
    float a1 = h ? ag1 : ap1;
    float a2 = h ? ag2 : ap2;
    float a3 = h ? ag3 : ap3;
    __half2 o01 = __floats2half2_rn(fmaxf(a0 * inv + b4.x, 0.f), fmaxf(a1 * inv + b4.y, 0.f));
    __half2 o23 = __floats2half2_rn(fmaxf(a2 * inv + b4.z, 0.f), fmaxf(a3 * inv + b4.w, 0.f));
    uint2 st;
    st.x = *(unsigned int*)&o01;
    st.y = *(unsigned int*)&o23;
    *(uint2*)(out + (long)v * 256 + h * 128 + c0) = st;
}

// ---------------------------------------------------------------------------
// Single-pass conv2 edge kernel v4 (H=1, C=64, fp16 xp).
// v2 chunk structure (16 edges / 4 gathers). Weight computed inline from
// asrc[s] (400KB, L2-resident) + adst[v] register: removes w2b stream +
// w2prep kernel. Quarter-waves: qw=lane>>4 takes edges j+4k+qw; m=lane&15
// gathers 8B (channels 4m..4m+3). Combine via shfl_xor(16,32).
// ---------------------------------------------------------------------------
__global__ __launch_bounds__(256) void conv2_edge(const int* __restrict__ rs, const int* __restrict__ csr,
                                                  const __half* __restrict__ xp,
                                                  const float* __restrict__ asrc,
                                                  const float* __restrict__ adst,
                                                  const float* __restrict__ bias,
                                                  float* __restrict__ out) {
    int v = blockIdx.x * 4 + (threadIdx.x >> 6);
    if (v >= NN) return;
    int lane = threadIdx.x & 63;
    int qw = lane >> 4;                // quarter-wave: edge offset
    int m = lane & 15;                 // channels 4m..4m+3
    int e0 = rs[v], e1 = rs[v + 1];
    const uint2* xp2 = (const uint2*)xp;

    float adv = adst[v];
    auto lrexp = [](float e) { e = (e > 0.f) ? e : NEG * e; return __expf(e); };

    float a0 = 0.f, a1 = 0.f, a2 = 0.f, a3 = 0.f, d = 0.f;

    int j = e0;
    // full chunks: 16 edges, 4 gathers in flight, no predication
    for (; j + 16 <= e1; j += 16) {
        int s[4]; float av[4]; uint2 r[4];
#pragma unroll
        for (int k = 0; k < 4; k++) s[k] = csr[j + 4 * k + qw];
#pragma unroll
        for (int k = 0; k < 4; k++) av[k] = asrc[s[k]];
#pragma unroll
        for (int k = 0; k < 4; k++) r[k] = xp2[(long)s[k] * 16 + m];
#pragma unroll
        for (int k = 0; k < 4; k++) {
            float w = lrexp(av[k] + adv);
            d += w;
            float2 x01 = __half22float2(*(__half2*)&r[k].x);
            float2 x23 = __half22float2(*(__half2*)&r[k].y);
            a0 += w * x01.x; a1 += w * x01.y;
            a2 += w * x23.x; a3 += w * x23.y;
        }
    }
    // tail: 4 edges per iteration, clamped
    for (; j < e1; j += 4) {
        int jj = j + qw;
        int jc = (jj < e1) ? jj : (e1 - 1);
        int s = csr[jc];
        float av = asrc[s];
        uint2 r = xp2[(long)s * 16 + m];
        float w = (jj < e1) ? lrexp(av + adv) : 0.f;
        d += w;
        float2 x01 = __half22float2(*(__half2*)&r.x);
        float2 x23 = __half22float2(*(__half2*)&r.y);
        a0 += w * x01.x; a1 += w * x01.y;
        a2 += w * x23.x; a3 += w * x23.y;
    }

    // combine the four quarters
    a0 += __shfl_xor(a0, 16); a1 += __shfl_xor(a1, 16);
    a2 += __shfl_xor(a2, 16); a3 += __shfl_xor(a3, 16);
    d  += __shfl_xor(d, 16);
    a0 += __shfl_xor(a0, 32); a1 += __shfl_xor(a1, 32);
    a2 += __shfl_xor(a2, 32); a3 += __shfl_xor(a3, 32);
    d  += __shfl_xor(d, 32);

    if (qw == 0) {
        float inv = 1.0f / d;
        float4 b4 = *(const float4*)&bias[4 * m];
        float4 o;
        o.x = a0 * inv + b4.x;
        o.y = a1 * inv + b4.y;
        o.z = a2 * inv + b4.z;
        o.w = a3 * inv + b4.w;
        *(float4*)&out[(long)v * 64 + 4 * m] = o;
    }
}

// ---------------------------------------------------------------------------
// Launch
// ---------------------------------------------------------------------------
extern "C" void kernel_launch(void* const* d_in, const int* in_sizes, int n_in,
                              void* d_out, int out_size, void* d_ws, size_t ws_size,
                              hipStream_t stream) {
    const float* x_ppi = (const float*)d_in[0];
    const float* x_go  = (const float*)d_in[1];
    const int*   ei    = (const int*)d_in[2];
    const float* W1    = (const float*)d_in[3];
    const float* as1   = (const float*)d_in[4];
    const float* ad1   = (const float*)d_in[5];
    const float* b1    = (const float*)d_in[6];
    const float* W2    = (const float*)d_in[7];
    const float* as2   = (const float*)d_in[8];
    const float* ad2   = (const float*)d_in[9];
    const float* b2    = (const float*)d_in[10];
    float* out = (float*)d_out;

    char* ws = (char*)d_ws;
    size_t off = 0;
    auto alloc = [&](size_t bytes) -> void* {
        void* p = ws + off;
        off = (off + bytes + 255) & ~(size_t)255;
        return p;
    };
    int* deg     = (int*)alloc((size_t)NN * 4);
    int* rs      = (int*)alloc((size_t)(NN + 1) * 4);
    int* cur     = (int*)alloc((size_t)NN * 4);
    int* part    = (int*)alloc(512 * 4);
    int* csr     = (int*)alloc((size_t)ET * 4);
    __half* xpc  = (__half*)alloc((size_t)NN * 256 * 2);   // packed {p0,p1,g0,g1} fp16
    __half* xp2  = (__half*)alloc((size_t)NN * 64 * 2);    // conv2 features fp16
    float2* atts = (float2*)alloc((size_t)NN * 4 * 8);
    float2* attd = (float2*)alloc((size_t)NN * 4 * 8);
    float* asr2  = (float*)alloc((size_t)NN * 4);
    float* ads2  = (float*)alloc((size_t)NN * 4);
    __half* hbuf = (__half*)alloc((size_t)NN * 256 * 2);   // conv1 output, fp16
    (void)ws_size; (void)in_sizes; (void)n_in; (void)out_size;

    const int NB = (NN + 255) / 256;        // 391
    const int EB = (ET + 255) / 256;        // 6641
    const int GB = (NN + 127) / 128;        // 782 (MFMA gemm blocks)

    // CSR build (shared by all three convs)
    hipMemsetAsync(deg, 0, (size_t)NN * 4, stream);
    k_count<<<EB, 256, 0, stream>>>(ei, deg);
    k_part<<<NB, 256, 0, stream>>>(deg, part);
    k_scanp<<<1, 512, 0, stream>>>(part, NB);
    k_scan<<<NB, 256, 0, stream>>>(deg, part, rs, cur);
    k_scatter<<<EB, 256, 0, stream>>>(ei, cur, csr);

    // layer 1: two MFMA GEMMs into packed fp16, fused attn, fused edge conv
    gemm_mfma<128, 128, 0, true><<<GB, 256, 0, stream>>>(x_ppi, W1, xpc, NN, 0);
    gemm_mfma<128, 128, 0, true><<<GB, 256, 0, stream>>>(x_go, W1, xpc, NN, 2);
    attn1_fused<<<(NN * 4 + 255) / 256, 256, 0, stream>>>((const __half2*)xpc, as1, ad1, atts, attd, NN);
    conv1_edge_fused<<<NN / 4, 256, 0, stream>>>(rs, csr, (const uint4*)xpc, atts, attd, b1, hbuf);

    // layer 2
    gemm_mfma<256, 64, 1, false><<<GB, 256, 0, stream>>>(hbuf, W2, xp2, NN, 0);
    attn2_kernel<<<(NN + 255) / 256, 256, 0, stream>>>((const __half2*)xp2, as2, ad2, asr2, ads2, NN);
    conv2_edge<<<NN / 4, 256, 0, stream>>>(rs, csr, xp2, asr2, ads2, b2, out);
}